// Round 12
// baseline (200.102 us; speedup 1.0000x reference)
//
#include <hip/hip_runtime.h>

#define NH 8
#define HD 32
#define NL 4
#define NP 4
#define DM 256
#define LEN_IN_C 13294
#define LQ_C 13294
#define B_C 2
#define M_TOTAL (B_C * LQ_C)           // 26588
#define MT_TILES 1662                  // ceil(26588/16)
#define GQ 32                          // queries per sampler block
#define QBLKS 831                      // ceil(26588/32)
#define LROWB 1040                     // fp32 LDS row stride: 1024 + 16 pad

typedef __attribute__((ext_vector_type(8))) short short8;
typedef __attribute__((ext_vector_type(4))) float floatx4;

__device__ __forceinline__ unsigned short f2bf(float x) {
    union { float f; unsigned int u; } a; a.f = x;
    unsigned int r = (a.u + 0x7FFFu + ((a.u >> 16) & 1u)) >> 16;
    return (unsigned short)r;
}
__device__ __forceinline__ unsigned short f2h(float x) {
    unsigned int r;
    asm("v_cvt_f16_f32 %0, %1" : "=v"(r) : "v"(x));
    return (unsigned short)r;
}
__device__ __forceinline__ unsigned int cvtpk_bf16(float lo, float hi) {
    unsigned int r;
    asm("v_cvt_pk_bf16_f32 %0, %1, %2" : "=v"(r) : "v"(lo), "v"(hi));
    return r;
}

// acc += f16(lo/hi half of v) * w   — one VALU op, f32 accumulate.
#define FMAMIX_LO(acc, v, w) \
    asm("v_fma_mix_f32 %0, %1, %2, %0 op_sel_hi:[1,0,0]" : "+v"(acc) : "v"(v), "v"(w))
#define FMAMIX_HI(acc, v, w) \
    asm("v_fma_mix_f32 %0, %1, %2, %0 op_sel:[1,0,0] op_sel_hi:[1,0,0]" : "+v"(acc) : "v"(v), "v"(w))

// 16-B async DMA: global -> LDS (dest = wave-uniform base + lane*16).
__device__ __forceinline__ void dma16(const float* g, float* l) {
    __builtin_amdgcn_global_load_lds(
        (const __attribute__((address_space(1))) unsigned int*)(g),
        (__attribute__((address_space(3))) unsigned int*)(l), 16, 0, 0);
}

// ---------------------------------------------------------------------------
// conv_a: query fp32 [M,256] -> swizzled bf16 A-fragments (round-0 layout).
// Unit u = (rt*8 + kc)*64 + lane; lane = m + 16*q holds A[rt*16+m][kc*32+q*8+j].
// Rows >= M are zeroed.
// ---------------------------------------------------------------------------
__global__ __launch_bounds__(256) void conv_a_kernel(const float* __restrict__ A,
                                                     unsigned short* __restrict__ Asw,
                                                     int M) {
    const int u = blockIdx.x * 256 + threadIdx.x;
    const int lane = u & 63;
    const int kc = (u >> 6) & 7;
    const int rt = u >> 9;
    const int row = rt * 16 + (lane & 15);
    const int col0 = kc * 32 + (lane >> 4) * 8;
    short8 v;
    if (row < M) {
        const float4 f0 = *(const float4*)(A + (size_t)row * 256 + col0);
        const float4 f1 = *(const float4*)(A + (size_t)row * 256 + col0 + 4);
        union { uint4 u4; short8 s; } c;
        c.u4.x = cvtpk_bf16(f0.x, f0.y); c.u4.y = cvtpk_bf16(f0.z, f0.w);
        c.u4.z = cvtpk_bf16(f1.x, f1.y); c.u4.w = cvtpk_bf16(f1.z, f1.w);
        v = c.s;
    } else {
        v = (short8){0, 0, 0, 0, 0, 0, 0, 0};
    }
    ((short8*)Asw)[u] = v;
}

// ---------------------------------------------------------------------------
// Weight conversions + pad/tail zeroing in ONE kernel.
//   BswV / BswO: standard swizzled B (16 nt-tiles).
//   BswH: per-head B for the fused off/attn GEMM.
//     layout: BswH[(h*24 + kc*3 + ct)*64 + lane], ct 0,1 = offset cols
//     h*32+ct*16.., ct 2 = logit cols h*16.. from Wattn.
// ---------------------------------------------------------------------------
__device__ __forceinline__ void conv_b_body(const float* __restrict__ W,
                                            unsigned short* __restrict__ Bsw,
                                            int Nsrc, int NTsrc, int NTtotal, int ntOff,
                                            int vblk) {
    const int u = vblk * 256 + threadIdx.x;
    const int lane = u & 63;
    const int unit = u >> 6;
    const int ntl = unit % NTsrc;
    const int kc = unit / NTsrc;
    const int n = ntl * 16 + (lane & 15);
    const int k0 = kc * 32 + (lane >> 4) * 8;
    short8 v;
#pragma unroll
    for (int j = 0; j < 8; ++j)
        v[j] = (short)f2bf(W[(size_t)(k0 + j) * Nsrc + n]);
    ((short8*)Bsw)[(size_t)(kc * NTtotal + ntOff + ntl) * 64 + lane] = v;
}

__global__ __launch_bounds__(256) void conv_weights_kernel(const float* __restrict__ Wv,
                                                           const float* __restrict__ Woff,
                                                           const float* __restrict__ Wattn,
                                                           const float* __restrict__ Wout,
                                                           unsigned short* __restrict__ BswV,
                                                           unsigned short* __restrict__ BswH,
                                                           unsigned short* __restrict__ BswO,
                                                           unsigned short* __restrict__ value,
                                                           unsigned short* __restrict__ AccSw) {
    const int blk = blockIdx.x;
    if (blk < 32)        conv_b_body(Wv,    BswV,  256, 16, 16, 0,  blk);
    else if (blk < 80) {
        // BswH: 192 units over 48 blocks
        const int u = (blk - 32) * 256 + threadIdx.x;
        const int lane = u & 63;
        const int unit = u >> 6;                  // 0..191
        const int h = unit / 24;
        const int rem = unit % 24;
        const int kc = rem / 3;
        const int ntl = rem % 3;
        const int colq = lane & 15;
        const int k0 = kc * 32 + (lane >> 4) * 8;
        const float* W = (ntl < 2) ? Woff : Wattn;
        const int Nsrc = (ntl < 2) ? 256 : 128;
        const int n = (ntl < 2) ? (h * 32 + ntl * 16 + colq) : (h * 16 + colq);
        short8 v;
#pragma unroll
        for (int j = 0; j < 8; ++j)
            v[j] = (short)f2bf(W[(size_t)(k0 + j) * Nsrc + n]);
        ((short8*)BswH)[(size_t)unit * 64 + lane] = v;
    }
    else if (blk < 112)  conv_b_body(Wout, BswO, 256, 16, 16, 0, blk - 80);
    else if (blk < 113) {
        const int t = threadIdx.x;
        if (t < 32) {
            value[-32 + t] = 0;                            // front pad (64 B)
            value[(size_t)M_TOTAL * 256 + t] = 0;          // back pad (64 B)
        }
    } else {
        // zero the tail rows 26588..26591 of AccSw (rt=1661, m=12..15)
        const int idx = threadIdx.x;
        if (idx < 128) {
            const int kc = idx >> 4;
            const int sub = idx & 15;
            const int lane = (12 + (sub & 3)) + 16 * (sub >> 2);
            const size_t unit = (size_t)(1661 * 8 + kc) * 64 + lane;
            short8 z = (short8){0, 0, 0, 0, 0, 0, 0, 0};
            ((short8*)AccSw)[unit] = z;
        }
    }
}

// ---------------------------------------------------------------------------
// Front GEMM (value projection only): 16-row DMA-staged fp32 A tile,
// 1662 blocks. bf16 pack at fragment-read time. Output FP16 head-major
// value layout value[((b*8+h)*LEN + pos)*32 + d].
// ---------------------------------------------------------------------------
__global__ __launch_bounds__(256) void front_gemm_kernel(const float* __restrict__ inflat,
                                                         const unsigned short* __restrict__ BswV,
                                                         const float* __restrict__ bv,
                                                         unsigned short* __restrict__ value, int M) {
    __shared__ float sA[16 * LROWB / 4];          // 16640 B
    const int tid = threadIdx.x;
    const int lane = tid & 63;
    const int wave = tid >> 6;
    const int trow = blockIdx.x * 16;

    // stage: each wave DMAs 4 rows (wave-uniform LDS base, per-lane source)
#pragma unroll
    for (int i = 0; i < 4; ++i) {
        const int lrow = i * 4 + wave;
        const int srow = min(trow + lrow, M - 1);
        dma16(inflat + (size_t)srow * 256 + lane * 4,
              (float*)((char*)sA + lrow * LROWB));
    }
    __syncthreads();                              // drains vmcnt -> tile ready

    const int m = lane & 15;
    const int q = lane >> 4;
    const short8* Bu = (const short8*)BswV;

    floatx4 acc[4];
#pragma unroll
    for (int t = 0; t < 4; ++t) acc[t] = (floatx4){0.f, 0.f, 0.f, 0.f};

#pragma unroll 2
    for (int kc = 0; kc < 8; ++kc) {
        const char* fb = (const char*)sA + m * LROWB + kc * 128 + q * 32;
        const float4 f0 = *(const float4*)fb;
        const float4 f1 = *(const float4*)(fb + 16);
        union { uint4 u; short8 s; } c;
        c.u.x = cvtpk_bf16(f0.x, f0.y); c.u.y = cvtpk_bf16(f0.z, f0.w);
        c.u.z = cvtpk_bf16(f1.x, f1.y); c.u.w = cvtpk_bf16(f1.z, f1.w);
        const short8 a = c.s;
#pragma unroll
        for (int t = 0; t < 4; ++t) {
            const short8 b = Bu[(size_t)(kc * 16 + wave * 4 + t) * 64 + lane];
            acc[t] = __builtin_amdgcn_mfma_f32_16x16x32_bf16(a, b, acc[t], 0, 0, 0);
        }
    }

    const int colq = lane & 15;
    const int rowq = (lane >> 4) * 4;
#pragma unroll
    for (int t = 0; t < 4; ++t) {
        const int col = (wave * 4 + t) * 16 + colq;
        const float bc = bv[col];
#pragma unroll
        for (int reg = 0; reg < 4; ++reg) {
            const int row = trow + rowq + reg;
            if (row < M) {
                const float v = acc[t][reg] + bc;
                const int bb = row >= LEN_IN_C;
                const int pos = row - (bb ? LEN_IN_C : 0);
                const int hh = col >> 5;
                const int dd = col & 31;
                value[((size_t)((bb << 3) + hh) * LEN_IN_C + pos) * 32 + dd] = f2h(v);
            }
        }
    }
}

// ---------------------------------------------------------------------------
// Back GEMM: column-split x2 -> 3324 blocks (16-row x 128-col tiles).
// ---------------------------------------------------------------------------
__global__ __launch_bounds__(256) void back_gemm_kernel(const unsigned short* __restrict__ Asw,
                                                        const unsigned short* __restrict__ Bsw,
                                                        const float* __restrict__ bias,
                                                        float* __restrict__ Cout, int M) {
    const int tid = threadIdx.x;
    const int lane = tid & 63;
    const int wave = tid >> 6;
    const int x = blockIdx.x;
    const int rt = x >> 1;
    const int half = x & 1;
    const int nt0 = half * 8 + wave * 2;

    const short8* Au = (const short8*)Asw;
    const short8* Bu = (const short8*)Bsw;

    floatx4 acc[2];
    acc[0] = (floatx4){0.f, 0.f, 0.f, 0.f};
    acc[1] = acc[0];

#pragma unroll 2
    for (int kc = 0; kc < 8; ++kc) {
        const short8 a = Au[(size_t)(rt * 8 + kc) * 64 + lane];
#pragma unroll
        for (int t = 0; t < 2; ++t) {
            const short8 b = Bu[(size_t)(kc * 16 + nt0 + t) * 64 + lane];
            acc[t] = __builtin_amdgcn_mfma_f32_16x16x32_bf16(a, b, acc[t], 0, 0, 0);
        }
    }

    const int colq = lane & 15;
    const int rowq = (lane >> 4) * 4;
#pragma unroll
    for (int t = 0; t < 2; ++t) {
        const int col = (nt0 + t) * 16 + colq;
        const float bc = bias[col];
#pragma unroll
        for (int reg = 0; reg < 4; ++reg) {
            const int row = rt * 16 + rowq + reg;
            if (row < M)
                Cout[(size_t)row * 256 + col] = acc[t][reg] + bc;
        }
    }
}

// ---------------------------------------------------------------------------
// Fused sampler v11: off/attn GEMM with A read DIRECTLY from pre-converted
// bf16 AswQ (global, coalesced, L2/L3-resident) — no staging phase.
//   Block = 32 queries x 1 head (head-per-XCD via wgid&7).
//   1. 6-tile MFMA (A from AswQ, B from BswH[h]) -> s_fused[32][50] (+bias).
//   2. Phase 1: 512 point-jobs read s_fused, build 16-B descriptors.
//   3. Phase 2: gather loop (FP16 value + v_fma_mix_f32).
// ---------------------------------------------------------------------------
__global__ __launch_bounds__(256, 6) void msda_fused_kernel(const float* __restrict__ refp,
                                                            const unsigned short* __restrict__ AswQ,
                                                            const unsigned short* __restrict__ value,
                                                            const unsigned short* __restrict__ BswH,
                                                            const float* __restrict__ boff,
                                                            const float* __restrict__ battn,
                                                            unsigned short* __restrict__ AccSw) {
    constexpr int lvl_hw[4] = {100, 50, 25, 13};
    constexpr int lvl_s[4] = {0, 10000, 12500, 13125};

    const int wg = blockIdx.x;
    const int h = wg & 7;
    const int q0 = (wg >> 3) * GQ;
    const int rt0 = (wg >> 3) * 2;                // query row-tiles rt0, rt0+1
    const int tid = threadIdx.x;
    const int lane = tid & 63;
    const int wave = tid >> 6;

    __shared__ float s_ref[GQ * 8];
    __shared__ float s_fused[GQ][50];
    __shared__ uint4 s_pdb[2 * GQ * 17];          // [side*GQ*17 + slot]

    s_ref[tid] = refp[min(q0 * 8 + tid, M_TOTAL * 8 - 1)];

    // ---- 1. GEMM: 6 tiles (r=i&1, ct=i>>1); wave w does i=w and i=w+4 ----
    {
        const short8* AuQ = (const short8*)AswQ;
        const short8* Bu = (const short8*)BswH;
        const int colq = lane & 15;
        const int rowq = (lane >> 4) * 4;
#pragma unroll
        for (int pass = 0; pass < 2; ++pass) {
            const int i = wave + pass * 4;
            if (i < 6) {
                const int r = i & 1;
                const int ct = i >> 1;
                floatx4 acc = (floatx4){0.f, 0.f, 0.f, 0.f};
#pragma unroll
                for (int kc = 0; kc < 8; ++kc) {
                    const short8 a = AuQ[(size_t)((rt0 + r) * 8 + kc) * 64 + lane];
                    const short8 b = Bu[(size_t)(h * 24 + kc * 3 + ct) * 64 + lane];
                    acc = __builtin_amdgcn_mfma_f32_16x16x32_bf16(a, b, acc, 0, 0, 0);
                }
                const float bc = (ct < 2) ? boff[h * 32 + ct * 16 + colq]
                                          : battn[h * 16 + colq];
#pragma unroll
                for (int reg = 0; reg < 4; ++reg)
                    s_fused[r * 16 + rowq + reg][ct * 16 + colq] = acc[reg] + bc;
            }
        }
    }
    __syncthreads();                              // s_fused ready

    // ---- 2. phase 1: build descriptors into s_pdb ----
#pragma unroll
    for (int jj = 0; jj < 2; ++jj) {
        const int job = jj * 256 + tid;          // 0..511
        const int qq = job >> 4;                 // 0..31
        const int t16 = job & 15;                // l*4+p
        const int l = t16 >> 2;
        const int bq = min(q0 + qq, M_TOTAL - 1);
        const int b = (bq >= LQ_C) ? 1 : 0;

        // softmax over the 16 (l,p) logits of head h (16 consecutive lanes)
        const float logit = s_fused[qq][32 + t16];
        float m = logit;
#pragma unroll
        for (int mask = 1; mask < 16; mask <<= 1) m = fmaxf(m, __shfl_xor(m, mask));
        const float e = __expf(logit - m);
        float s = e;
#pragma unroll
        for (int mask = 1; mask < 16; mask <<= 1) s += __shfl_xor(s, mask);
        const float aw = e / s;

        const int whl = lvl_hw[l];
        const float fwh = (float)whl;
        const float ox = s_fused[qq][t16 * 2];
        const float oy = s_fused[qq][t16 * 2 + 1];
        const float x = s_ref[qq * 8 + l * 2] * fwh + ox - 0.5f;
        const float y = s_ref[qq * 8 + l * 2 + 1] * fwh + oy - 0.5f;
        const float x0f = floorf(x), y0f = floorf(y);
        const float tx = x - x0f, ty = y - y0f;
        const int ix0 = (int)x0f, iy0 = (int)y0f;

        const bool xv0 = (unsigned)ix0 < (unsigned)whl;
        const bool xv1 = (unsigned)(ix0 + 1) < (unsigned)whl;
        const bool yv0 = (unsigned)iy0 < (unsigned)whl;
        const bool yv1 = (unsigned)(iy0 + 1) < (unsigned)whl;

        // pair base x: clamp to [-1, w-1]; invalid halves carry zero weight
        const int cxp = min(max(ix0, -1), whl - 1);
        const int cy0 = min(max(iy0, 0), whl - 1);
        const int cy1 = min(max(iy0 + 1, 0), whl - 1);

        const int posb = (b * 8 + h) * LEN_IN_C + lvl_s[l];
        const int offT = (posb + cy0 * whl + cxp) * 64;   // BYTE offsets, 128-B pairs
        const int offB = (posb + cy1 * whl + cxp) * 64;
        const float w00 = (xv0 && yv0) ? aw * (1.f - tx) * (1.f - ty) : 0.f;
        const float w01 = (xv1 && yv0) ? aw * tx * (1.f - ty) : 0.f;
        const float w10 = (xv0 && yv1) ? aw * (1.f - tx) * ty : 0.f;
        const float w11 = (xv1 && yv1) ? aw * tx * ty : 0.f;
        const int slot = qq * 17 + t16;
        uint4 d0, d1;
        d0.x = (unsigned)offT; d0.y = (unsigned)offB;
        d0.z = __float_as_uint(w00); d0.w = __float_as_uint(w10);   // left corner
        d1.x = (unsigned)offT; d1.y = (unsigned)offB;
        d1.z = __float_as_uint(w01); d1.w = __float_as_uint(w11);   // right corner
        s_pdb[slot] = d0;
        s_pdb[GQ * 17 + slot] = d1;
    }
    __syncthreads();

    // ---- 3. phase 2: gather + weighted accumulate ----
    const int qq = tid >> 3;
    const int l8 = tid & 7;
    const char* vbp = (const char*)value + l8 * 16;
    const int side = (l8 >> 2) & 1;
    const uint4* pd = s_pdb + side * (GQ * 17) + qq * 17;

    float a0 = 0.f, a1 = 0.f, a2 = 0.f, a3 = 0.f;
    float a4 = 0.f, a5 = 0.f, a6 = 0.f, a7 = 0.f;
#pragma unroll 2
    for (int pt = 0; pt < 16; ++pt) {
        const uint4 d = pd[pt];
        const float wt = __uint_as_float(d.z);
        const float wb = __uint_as_float(d.w);
        const uint4 vt = *(const uint4*)(vbp + (int)d.x);
        const uint4 vb = *(const uint4*)(vbp + (int)d.y);
        FMAMIX_LO(a0, vt.x, wt); FMAMIX_HI(a1, vt.x, wt);
        FMAMIX_LO(a2, vt.y, wt); FMAMIX_HI(a3, vt.y, wt);
        FMAMIX_LO(a4, vt.z, wt); FMAMIX_HI(a5, vt.z, wt);
        FMAMIX_LO(a6, vt.w, wt); FMAMIX_HI(a7, vt.w, wt);
        FMAMIX_LO(a0, vb.x, wb); FMAMIX_HI(a1, vb.x, wb);
        FMAMIX_LO(a2, vb.y, wb); FMAMIX_HI(a3, vb.y, wb);
        FMAMIX_LO(a4, vb.z, wb); FMAMIX_HI(a5, vb.z, wb);
        FMAMIX_LO(a6, vb.w, wb); FMAMIX_HI(a7, vb.w, wb);
    }

    a0 += __shfl_xor(a0, 4); a1 += __shfl_xor(a1, 4);
    a2 += __shfl_xor(a2, 4); a3 += __shfl_xor(a3, 4);
    a4 += __shfl_xor(a4, 4); a5 += __shfl_xor(a5, 4);
    a6 += __shfl_xor(a6, 4); a7 += __shfl_xor(a7, 4);

    const int bq = q0 + qq;
    if (side == 0 && bq < M_TOTAL) {
        // write swizzled A-fragment: row = bq, col = h*32 + (l8&3)*8 (+0..7)
        const int rt = bq >> 4, mm = bq & 15;
        const int unit = (rt * 8 + h) * 64 + ((l8 & 3) * 16 + mm);
        uint4 o;
        o.x = cvtpk_bf16(a0, a1);
        o.y = cvtpk_bf16(a2, a3);
        o.z = cvtpk_bf16(a4, a5);
        o.w = cvtpk_bf16(a6, a7);
        *(uint4*)(AccSw + (size_t)unit * 8) = o;
    }
}

extern "C" void kernel_launch(void* const* d_in, const int* in_sizes, int n_in,
                              void* d_out, int out_size, void* d_ws, size_t ws_size,
                              hipStream_t stream) {
    const float* query  = (const float*)d_in[0];
    const float* refp   = (const float*)d_in[1];
    const float* inflat = (const float*)d_in[2];
    const float* Wv    = (const float*)d_in[4];
    const float* bv    = (const float*)d_in[5];
    const float* Woff  = (const float*)d_in[6];
    const float* boff  = (const float*)d_in[7];
    const float* Wattn = (const float*)d_in[8];
    const float* battn = (const float*)d_in[9];
    const float* Wout  = (const float*)d_in[10];
    const float* bout  = (const float*)d_in[11];
    float* out = (float*)d_out;

    char* p = (char*)d_ws;
    unsigned short* AccSw = (unsigned short*)p;
    p += (size_t)MT_TILES * 8 * 64 * 8 * sizeof(unsigned short);          // 13.6 MB
    unsigned short* AswQ = (unsigned short*)p;
    p += (size_t)MT_TILES * 8 * 64 * 8 * sizeof(unsigned short);          // 13.6 MB
    unsigned short* BswV = (unsigned short*)p;   p += (size_t)8 * 16 * 64 * 8 * 2;
    unsigned short* BswH = (unsigned short*)p;   p += (size_t)192 * 64 * 8 * 2;
    unsigned short* BswO = (unsigned short*)p;   p += (size_t)8 * 16 * 64 * 8 * 2;
    unsigned short* value = (unsigned short*)p + 32;                      // 64 B front pad
    p += ((size_t)M_TOTAL * 256 + 64) * sizeof(unsigned short);           // + 64 B back pad

    const int M = M_TOTAL;

    conv_weights_kernel<<<114, 256, 0, stream>>>(Wv, Woff, Wattn, Wout,
                                                 BswV, BswH, BswO, value, AccSw);
    conv_a_kernel<<<MT_TILES * 2, 256, 0, stream>>>(query, AswQ, M);
    front_gemm_kernel<<<MT_TILES, 256, 0, stream>>>(inflat, BswV, bv, value, M);
    msda_fused_kernel<<<QBLKS * 8, 256, 0, stream>>>(refp, AswQ, value, BswH,
                                                     boff, battn, AccSw);
    back_gemm_kernel<<<MT_TILES * 2, 256, 0, stream>>>(AccSw, BswO, bout, out, M);
}

// Round 13
// 190.676 us; speedup vs baseline: 1.0494x; 1.0494x over previous
//
#include <hip/hip_runtime.h>

#define NH 8
#define HD 32
#define NL 4
#define NP 4
#define DM 256
#define LEN_IN_C 13294
#define LQ_C 13294
#define B_C 2
#define M_TOTAL (B_C * LQ_C)           // 26588
#define MT_TILES 1662                  // ceil(26588/16)
#define RT32_TILES 831                 // ceil(26588/32)
#define GQ 32                          // queries per sampler block
#define QBLKS 831                      // ceil(26588/32)
#define LROWB 1040                     // fp32 LDS row stride: 1024 + 16 pad

typedef __attribute__((ext_vector_type(8))) short short8;
typedef __attribute__((ext_vector_type(4))) float floatx4;

__device__ __forceinline__ unsigned short f2bf(float x) {
    union { float f; unsigned int u; } a; a.f = x;
    unsigned int r = (a.u + 0x7FFFu + ((a.u >> 16) & 1u)) >> 16;
    return (unsigned short)r;
}
__device__ __forceinline__ unsigned short f2h(float x) {
    unsigned int r;
    asm("v_cvt_f16_f32 %0, %1" : "=v"(r) : "v"(x));
    return (unsigned short)r;
}
__device__ __forceinline__ unsigned int cvtpk_bf16(float lo, float hi) {
    unsigned int r;
    asm("v_cvt_pk_bf16_f32 %0, %1, %2" : "=v"(r) : "v"(lo), "v"(hi));
    return r;
}

// acc += f16(lo/hi half of v) * w   — one VALU op, f32 accumulate.
#define FMAMIX_LO(acc, v, w) \
    asm("v_fma_mix_f32 %0, %1, %2, %0 op_sel_hi:[1,0,0]" : "+v"(acc) : "v"(v), "v"(w))
#define FMAMIX_HI(acc, v, w) \
    asm("v_fma_mix_f32 %0, %1, %2, %0 op_sel:[1,0,0] op_sel_hi:[1,0,0]" : "+v"(acc) : "v"(v), "v"(w))

// 16-B async DMA: global -> LDS (dest = wave-uniform base + lane*16).
__device__ __forceinline__ void dma16(const float* g, float* l) {
    __builtin_amdgcn_global_load_lds(
        (const __attribute__((address_space(1))) unsigned int*)(g),
        (__attribute__((address_space(3))) unsigned int*)(l), 16, 0, 0);
}

// ---------------------------------------------------------------------------
// Weight conversions + bias fuse + pad/tail zeroing in ONE kernel.
// ---------------------------------------------------------------------------
__device__ __forceinline__ void conv_b_body(const float* __restrict__ W,
                                            unsigned short* __restrict__ Bsw,
                                            int Nsrc, int NTsrc, int NTtotal, int ntOff,
                                            int vblk) {
    const int u = vblk * 256 + threadIdx.x;
    const int lane = u & 63;
    const int unit = u >> 6;
    const int ntl = unit % NTsrc;
    const int kc = unit / NTsrc;
    const int n = ntl * 16 + (lane & 15);
    const int k0 = kc * 32 + (lane >> 4) * 8;
    short8 v;
#pragma unroll
    for (int j = 0; j < 8; ++j)
        v[j] = (short)f2bf(W[(size_t)(k0 + j) * Nsrc + n]);
    ((short8*)Bsw)[(size_t)(kc * NTtotal + ntOff + ntl) * 64 + lane] = v;
}

__global__ __launch_bounds__(256) void conv_weights_kernel(const float* __restrict__ Wv,
                                                           const float* __restrict__ Woff,
                                                           const float* __restrict__ Wattn,
                                                           const float* __restrict__ Wout,
                                                           const float* __restrict__ boff,
                                                           const float* __restrict__ battn,
                                                           unsigned short* __restrict__ BswV,
                                                           unsigned short* __restrict__ BswOA,
                                                           unsigned short* __restrict__ BswO,
                                                           float* __restrict__ fbias,
                                                           unsigned short* __restrict__ value,
                                                           unsigned short* __restrict__ AccSw) {
    const int blk = blockIdx.x;
    if (blk < 32)        conv_b_body(Wv,    BswV,  256, 16, 16, 0,  blk);
    else if (blk < 64)   conv_b_body(Woff,  BswOA, 256, 16, 24, 0,  blk - 32);
    else if (blk < 80)   conv_b_body(Wattn, BswOA, 128,  8, 24, 16, blk - 64);
    else if (blk < 112)  conv_b_body(Wout,  BswO,  256, 16, 16, 0,  blk - 80);
    else if (blk < 114) {
        const int t = (blk - 112) * 256 + threadIdx.x;
        if (t < 384) fbias[t] = (t < 256) ? boff[t] : battn[t - 256];
        else if (t < 416) {
            const int j = t - 384;
            value[-32 + j] = 0;                            // front pad (64 B)
            value[(size_t)M_TOTAL * 256 + j] = 0;          // back pad (64 B)
        }
    } else {
        // zero the tail rows 26588..26591 of AccSw (rt=1661, m=12..15)
        const int idx = threadIdx.x;
        if (idx < 128) {
            const int kc = idx >> 4;
            const int sub = idx & 15;
            const int lane = (12 + (sub & 3)) + 16 * (sub >> 2);
            const size_t unit = (size_t)(1661 * 8 + kc) * 64 + lane;
            short8 z = (short8){0, 0, 0, 0, 0, 0, 0, 0};
            ((short8*)AccSw)[unit] = z;
        }
    }
}

// ---------------------------------------------------------------------------
// Front GEMM (round-8 proven): DMA-staged fp32 A tile (32 x 256, row stride
// 1040 B), bf16 pack at fragment-read time, 1662 even/odd blocks.
// OUTMODE 0: fp32 row-major [M, NT*16].  OUTMODE 1: FP16 head-major value
//   layout value[((b*8+h)*LEN + pos)*32 + d].
// ---------------------------------------------------------------------------
template <int NT, int OUTMODE>
__device__ __forceinline__ void tile_compute_f32lds(const float* __restrict__ sA,
                                                    const unsigned short* __restrict__ Bsw,
                                                    const float* __restrict__ bias,
                                                    void* __restrict__ Cout, int M, int trow,
                                                    int lane, int wave) {
    constexpr int NTW = NT / 4;
    const int m = lane & 15;
    const int q = lane >> 4;
    const short8* Bu = (const short8*)Bsw;

    floatx4 acc[2][NTW];
#pragma unroll
    for (int r = 0; r < 2; ++r)
#pragma unroll
        for (int t = 0; t < NTW; ++t) acc[r][t] = (floatx4){0.f, 0.f, 0.f, 0.f};

#pragma unroll 2
    for (int kc = 0; kc < 8; ++kc) {
        short8 a[2];
#pragma unroll
        for (int r = 0; r < 2; ++r) {
            const char* fb = (const char*)sA + (m + r * 16) * LROWB + kc * 128 + q * 32;
            const float4 f0 = *(const float4*)fb;
            const float4 f1 = *(const float4*)(fb + 16);
            union { uint4 u; short8 s; } c;
            c.u.x = cvtpk_bf16(f0.x, f0.y); c.u.y = cvtpk_bf16(f0.z, f0.w);
            c.u.z = cvtpk_bf16(f1.x, f1.y); c.u.w = cvtpk_bf16(f1.z, f1.w);
            a[r] = c.s;
        }
#pragma unroll
        for (int t = 0; t < NTW; ++t) {
            const short8 b = Bu[(size_t)(kc * NT + wave * NTW + t) * 64 + lane];
            acc[0][t] = __builtin_amdgcn_mfma_f32_16x16x32_bf16(a[0], b, acc[0][t], 0, 0, 0);
            acc[1][t] = __builtin_amdgcn_mfma_f32_16x16x32_bf16(a[1], b, acc[1][t], 0, 0, 0);
        }
    }

    const int N = NT * 16;
    const int colq = lane & 15;
    const int rowq = (lane >> 4) * 4;
#pragma unroll
    for (int t = 0; t < NTW; ++t) {
        const int col = (wave * NTW + t) * 16 + colq;
        const float bc = bias[col];
#pragma unroll
        for (int r = 0; r < 2; ++r) {
#pragma unroll
            for (int reg = 0; reg < 4; ++reg) {
                const int row = trow + r * 16 + rowq + reg;
                if (row < M) {
                    const float v = acc[r][t][reg] + bc;
                    if (OUTMODE == 1) {
                        const int bb = row >= LEN_IN_C;
                        const int pos = row - (bb ? LEN_IN_C : 0);
                        const int hh = col >> 5;
                        const int dd = col & 31;
                        ((unsigned short*)Cout)[((size_t)((bb << 3) + hh) * LEN_IN_C + pos) * 32 + dd] = f2h(v);
                    } else {
                        ((float*)Cout)[(size_t)row * N + col] = v;
                    }
                }
            }
        }
    }
}

__global__ __launch_bounds__(256) void front_gemm_kernel(const float* __restrict__ inflat,
                                                         const float* __restrict__ query,
                                                         const unsigned short* __restrict__ BswV,
                                                         const unsigned short* __restrict__ BswOA,
                                                         const float* __restrict__ bv,
                                                         const float* __restrict__ fbias,
                                                         unsigned short* __restrict__ value,
                                                         float* __restrict__ fused, int M) {
    __shared__ float sA[32 * LROWB / 4];          // 33280 B
    const int tid = threadIdx.x;
    const int lane = tid & 63;
    const int wave = tid >> 6;
    const int x = blockIdx.x;
    const int flavor = x & 1;                     // 0: value GEMM, 1: off/attn GEMM
    const int trow = (x >> 1) * 32;
    const float* A = flavor ? query : inflat;

    // stage: each wave DMAs 8 rows (wave-uniform LDS base, per-lane source)
#pragma unroll
    for (int i = 0; i < 8; ++i) {
        const int lrow = i * 4 + wave;
        const int srow = min(trow + lrow, M - 1);
        dma16(A + (size_t)srow * 256 + lane * 4,
              (float*)((char*)sA + lrow * LROWB));
    }
    __syncthreads();                              // drains vmcnt -> tile ready

    if (flavor == 0)
        tile_compute_f32lds<16, 1>(sA, BswV, bv, (void*)value, M, trow, lane, wave);
    else
        tile_compute_f32lds<24, 0>(sA, BswOA, fbias, (void*)fused, M, trow, lane, wave);
}

// ---------------------------------------------------------------------------
// Back GEMM (round-8 proven): pre-swizzled bf16 A, two 16-row tiles per
// block, 831 blocks, plain unroll-2 kc loop.
// ---------------------------------------------------------------------------
__global__ __launch_bounds__(256) void back_gemm_kernel(const unsigned short* __restrict__ Asw,
                                                        const unsigned short* __restrict__ Bsw,
                                                        const float* __restrict__ bias,
                                                        float* __restrict__ Cout, int M) {
    constexpr int NT = 16;
    constexpr int NTW = 4;
    const int tid = threadIdx.x;
    const int lane = tid & 63;
    const int wave = tid >> 6;
    const int rt0 = blockIdx.x * 2;

    const short8* Au = (const short8*)Asw;
    const short8* Bu = (const short8*)Bsw;

    floatx4 acc[2][NTW];
#pragma unroll
    for (int r = 0; r < 2; ++r)
#pragma unroll
        for (int t = 0; t < NTW; ++t) acc[r][t] = (floatx4){0.f, 0.f, 0.f, 0.f};

#pragma unroll 2
    for (int kc = 0; kc < 8; ++kc) {
        const short8 a0 = Au[(size_t)(rt0 * 8 + kc) * 64 + lane];
        const short8 a1 = Au[(size_t)((rt0 + 1) * 8 + kc) * 64 + lane];
#pragma unroll
        for (int t = 0; t < NTW; ++t) {
            const short8 b = Bu[(size_t)(kc * NT + wave * NTW + t) * 64 + lane];
            acc[0][t] = __builtin_amdgcn_mfma_f32_16x16x32_bf16(a0, b, acc[0][t], 0, 0, 0);
            acc[1][t] = __builtin_amdgcn_mfma_f32_16x16x32_bf16(a1, b, acc[1][t], 0, 0, 0);
        }
    }

    const int colq = lane & 15;
    const int rowq = (lane >> 4) * 4;
#pragma unroll
    for (int t = 0; t < NTW; ++t) {
        const int col = (wave * NTW + t) * 16 + colq;
        const float bc = bias[col];
#pragma unroll
        for (int r = 0; r < 2; ++r) {
#pragma unroll
            for (int reg = 0; reg < 4; ++reg) {
                const int row = (rt0 + r) * 16 + rowq + reg;
                if (row < M)
                    Cout[(size_t)row * 256 + col] = acc[r][t][reg] + bc;
            }
        }
    }
}

// ---------------------------------------------------------------------------
// Sampler v9 (round-9 proven, best-measured): head-per-XCD + FP16 value +
// v_fma_mix_f32 + fused 16-B LDS point-descriptor; non-chunked loop at
// (256,8) occupancy, __expf softmax.
// ---------------------------------------------------------------------------
__global__ __launch_bounds__(256, 8) void msda_sample_kernel(const float* __restrict__ refp,
                                                             const unsigned short* __restrict__ value,
                                                             const float* __restrict__ fused,
                                                             unsigned short* __restrict__ AccSw) {
    constexpr int lvl_hw[4] = {100, 50, 25, 13};
    constexpr int lvl_s[4] = {0, 10000, 12500, 13125};

    const int wg = blockIdx.x;
    const int h = wg & 7;
    const int q0 = (wg >> 3) * GQ;
    const int tid = threadIdx.x;

    __shared__ float s_ref[GQ * 8];
    __shared__ uint4 s_pd[2][GQ * 17];

    s_ref[tid] = refp[min(q0 * 8 + tid, M_TOTAL * 8 - 1)];
    __syncthreads();

#pragma unroll
    for (int jj = 0; jj < 2; ++jj) {
        const int job = jj * 256 + tid;          // 0..511
        const int qq = job >> 4;                 // 0..31
        const int t16 = job & 15;                // l*4+p
        const int l = t16 >> 2;
        const int bq = min(q0 + qq, M_TOTAL - 1);
        const int b = (bq >= LQ_C) ? 1 : 0;

        // softmax over the 16 (l,p) logits of head h (16 consecutive lanes)
        const float logit = fused[(size_t)bq * 384 + 256 + h * 16 + t16];
        float m = logit;
#pragma unroll
        for (int mask = 1; mask < 16; mask <<= 1) m = fmaxf(m, __shfl_xor(m, mask));
        const float e = __expf(logit - m);
        float s = e;
#pragma unroll
        for (int mask = 1; mask < 16; mask <<= 1) s += __shfl_xor(s, mask);
        const float aw = e / s;

        const int whl = lvl_hw[l];
        const float fwh = (float)whl;
        const float2 oxy = *(const float2*)(fused + (size_t)bq * 384 + (h * 16 + t16) * 2);
        const float x = s_ref[qq * 8 + l * 2] * fwh + oxy.x - 0.5f;
        const float y = s_ref[qq * 8 + l * 2 + 1] * fwh + oxy.y - 0.5f;
        const float x0f = floorf(x), y0f = floorf(y);
        const float tx = x - x0f, ty = y - y0f;
        const int ix0 = (int)x0f, iy0 = (int)y0f;

        const bool xv0 = (unsigned)ix0 < (unsigned)whl;
        const bool xv1 = (unsigned)(ix0 + 1) < (unsigned)whl;
        const bool yv0 = (unsigned)iy0 < (unsigned)whl;
        const bool yv1 = (unsigned)(iy0 + 1) < (unsigned)whl;

        // pair base x: clamp to [-1, w-1]; invalid halves carry zero weight
        const int cxp = min(max(ix0, -1), whl - 1);
        const int cy0 = min(max(iy0, 0), whl - 1);
        const int cy1 = min(max(iy0 + 1, 0), whl - 1);

        const int posb = (b * 8 + h) * LEN_IN_C + lvl_s[l];
        const int offT = (posb + cy0 * whl + cxp) * 64;   // BYTE offsets, 128-B pairs
        const int offB = (posb + cy1 * whl + cxp) * 64;
        const float w00 = (xv0 && yv0) ? aw * (1.f - tx) * (1.f - ty) : 0.f;
        const float w01 = (xv1 && yv0) ? aw * tx * (1.f - ty) : 0.f;
        const float w10 = (xv0 && yv1) ? aw * (1.f - tx) * ty : 0.f;
        const float w11 = (xv1 && yv1) ? aw * tx * ty : 0.f;
        const int slot = qq * 17 + t16;
        uint4 d0, d1;
        d0.x = (unsigned)offT; d0.y = (unsigned)offB;
        d0.z = __float_as_uint(w00); d0.w = __float_as_uint(w10);   // left corner
        d1.x = (unsigned)offT; d1.y = (unsigned)offB;
        d1.z = __float_as_uint(w01); d1.w = __float_as_uint(w11);   // right corner
        s_pd[0][slot] = d0;
        s_pd[1][slot] = d1;
    }
    __syncthreads();

    const int qq = tid >> 3;
    const int l8 = tid & 7;
    const char* vbp = (const char*)value + l8 * 16;
    const int pbase = qq * 17;
    const int side = (l8 >> 2) & 1;

    float a0 = 0.f, a1 = 0.f, a2 = 0.f, a3 = 0.f;
    float a4 = 0.f, a5 = 0.f, a6 = 0.f, a7 = 0.f;
#pragma unroll 2
    for (int pt = 0; pt < 16; ++pt) {
        const uint4 d = s_pd[side][pbase + pt];
        const float wt = __uint_as_float(d.z);
        const float wb = __uint_as_float(d.w);
        const uint4 vt = *(const uint4*)(vbp + (int)d.x);
        const uint4 vb = *(const uint4*)(vbp + (int)d.y);
        FMAMIX_LO(a0, vt.x, wt); FMAMIX_HI(a1, vt.x, wt);
        FMAMIX_LO(a2, vt.y, wt); FMAMIX_HI(a3, vt.y, wt);
        FMAMIX_LO(a4, vt.z, wt); FMAMIX_HI(a5, vt.z, wt);
        FMAMIX_LO(a6, vt.w, wt); FMAMIX_HI(a7, vt.w, wt);
        FMAMIX_LO(a0, vb.x, wb); FMAMIX_HI(a1, vb.x, wb);
        FMAMIX_LO(a2, vb.y, wb); FMAMIX_HI(a3, vb.y, wb);
        FMAMIX_LO(a4, vb.z, wb); FMAMIX_HI(a5, vb.z, wb);
        FMAMIX_LO(a6, vb.w, wb); FMAMIX_HI(a7, vb.w, wb);
    }

    a0 += __shfl_xor(a0, 4); a1 += __shfl_xor(a1, 4);
    a2 += __shfl_xor(a2, 4); a3 += __shfl_xor(a3, 4);
    a4 += __shfl_xor(a4, 4); a5 += __shfl_xor(a5, 4);
    a6 += __shfl_xor(a6, 4); a7 += __shfl_xor(a7, 4);

    const int bq = q0 + qq;
    if (side == 0 && bq < M_TOTAL) {
        // write swizzled A-fragment: row = bq, col = h*32 + (l8&3)*8 (+0..7)
        const int rt = bq >> 4, mm = bq & 15;
        const int unit = (rt * 8 + h) * 64 + ((l8 & 3) * 16 + mm);
        uint4 o;
        o.x = cvtpk_bf16(a0, a1);
        o.y = cvtpk_bf16(a2, a3);
        o.z = cvtpk_bf16(a4, a5);
        o.w = cvtpk_bf16(a6, a7);
        *(uint4*)(AccSw + (size_t)unit * 8) = o;
    }
}

extern "C" void kernel_launch(void* const* d_in, const int* in_sizes, int n_in,
                              void* d_out, int out_size, void* d_ws, size_t ws_size,
                              hipStream_t stream) {
    const float* query  = (const float*)d_in[0];
    const float* refp   = (const float*)d_in[1];
    const float* inflat = (const float*)d_in[2];
    const float* Wv    = (const float*)d_in[4];
    const float* bv    = (const float*)d_in[5];
    const float* Woff  = (const float*)d_in[6];
    const float* boff  = (const float*)d_in[7];
    const float* Wattn = (const float*)d_in[8];
    const float* battn = (const float*)d_in[9];
    const float* Wout  = (const float*)d_in[10];
    const float* bout  = (const float*)d_in[11];
    float* out = (float*)d_out;

    char* p = (char*)d_ws;
    unsigned short* AccSw = (unsigned short*)p;
    p += (size_t)MT_TILES * 8 * 64 * 8 * sizeof(unsigned short);          // 13.6 MB
    unsigned short* BswV = (unsigned short*)p;   p += (size_t)8 * 16 * 64 * 8 * 2;
    unsigned short* BswOA = (unsigned short*)p;  p += (size_t)8 * 24 * 64 * 8 * 2;
    unsigned short* BswO = (unsigned short*)p;   p += (size_t)8 * 16 * 64 * 8 * 2;
    float* fbias = (float*)p;                    p += 384 * sizeof(float);
    unsigned short* value = (unsigned short*)p + 32;                      // 64 B front pad
    p += ((size_t)M_TOTAL * 256 + 64) * sizeof(unsigned short);           // + 64 B back pad
    float* fused = (float*)p;                    p += (size_t)M_TOTAL * 384 * 4;

    const int M = M_TOTAL;

    conv_weights_kernel<<<115, 256, 0, stream>>>(Wv, Woff, Wattn, Wout, boff, battn,
                                                 BswV, BswOA, BswO, fbias, value, AccSw);
    front_gemm_kernel<<<RT32_TILES * 2, 256, 0, stream>>>(inflat, query, BswV, BswOA,
                                                          bv, fbias, value, fused, M);
    msda_sample_kernel<<<QBLKS * 8, 256, 0, stream>>>(refp, value, fused, AccSw);
    back_gemm_kernel<<<RT32_TILES, 256, 0, stream>>>(AccSw, BswO, bout, out, M);
}